// Round 21
// baseline (113.436 us; speedup 1.0000x reference)
//
#include <hip/hip_runtime.h>
#include <hip/hip_bf16.h>

#define Hn 224
#define HWn (224*224)
#define B_ 16
#define CIN_ 64
#define COUT_ 64
#define PCr 240                 // rev row stride (bf16 elems)
#define PRr 230                 // rows: img -2..227 (rowpad = img+2)
#define PHWr (PRr*PCr)          // per-image u16 elems
#define CE 232                  // rev const, even-parity copy (serves even lo5)
#define CO 233                  // odd-parity copy (serves odd lo5)
#define RE_OFF ((1<<20) + 512)  // byte offsets in d_ws (512 covers rowpad=-1 guard)
#define RO_OFF ((3<<20) + 512)
#define W_OFF  (6<<20)

typedef __attribute__((ext_vector_type(4)))  float f32x4;
typedef __attribute__((ext_vector_type(8)))  short bf16x8;
typedef __attribute__((ext_vector_type(16))) float f32x16;

// Store one 4-px quad (img cols c0..c0+3, values v0..v3 packed in q0=pk(v1,v0),
// q1=pk(v3,v2)) into both reversed bf16 buffers at row rowpad.
// Re (C=232): start idx 229-c0 (odd) -> 4 u16 stores. Ro (C=233): start 230-c0
// (even) -> 2 u32 stores. Rev-ascending = img-descending: v3,v2,v1,v0.
__device__ __forceinline__ void store_quad(unsigned short* Re, unsigned short* Ro,
                                           int rowpad, int c0,
                                           unsigned int q0, unsigned int q1) {
    unsigned short* pe = Re + rowpad * PCr + (CE - c0 - 3);
    pe[0] = (unsigned short)q1;          // v3
    pe[1] = (unsigned short)(q1 >> 16);  // v2
    pe[2] = (unsigned short)q0;          // v1
    pe[3] = (unsigned short)(q0 >> 16);  // v0
    unsigned int* po = (unsigned int*)(Ro + rowpad * PCr + (CO - c0 - 3));
    po[0] = q1;                          // (v3,v2)
    po[1] = q0;                          // (v1,v0)
}

// Kernel 1 (merged): blocks 0..783 = channel-sum -> reversed bf16 S copies
// (+ inline circular halos, cols -4..227 / rows -2..227); nt x-loads (R12 win).
// Blocks 784..799 = W' prep.
__global__ __launch_bounds__(256) void chan_sum_kernel(const float* __restrict__ x,
                                                       unsigned short* __restrict__ Re,
                                                       unsigned short* __restrict__ Ro,
                                                       const float* __restrict__ K,
                                                       unsigned short* __restrict__ W) {
    if (blockIdx.x >= 784) {            // ---- wprep tail blocks ----
        int i = (blockIdx.x - 784) * 256 + threadIdx.x;   // 0..4095
        int oc = i >> 6, kk = i & 63;
        int ky = kk >> 3, kx = kk & 7;
        float v = (ky < 7 && kx < 7) ? K[(size_t)oc * (CIN_ * 49) + ky * 7 + kx] : 0.0f;
        __hip_bfloat16 h = __float2bfloat16(v);
        W[i] = *(unsigned short*)&h;
        return;
    }

    int idx = blockIdx.x * 256 + threadIdx.x;   // < 200704 exactly
    const int s4 = HWn / 4;
    int b  = idx / s4;
    int p4 = idx - b * s4;
    const f32x4* xb = (const f32x4*)x + (size_t)b * CIN_ * s4 + p4;

    f32x4 a0 = __builtin_nontemporal_load(xb + 0 * s4);
    f32x4 a1 = __builtin_nontemporal_load(xb + 1 * s4);
    f32x4 a2 = __builtin_nontemporal_load(xb + 2 * s4);
    f32x4 a3 = __builtin_nontemporal_load(xb + 3 * s4);
    #pragma unroll 4
    for (int c = 4; c < CIN_; c += 4) {
        a0 += __builtin_nontemporal_load(xb + (size_t)(c + 0) * s4);
        a1 += __builtin_nontemporal_load(xb + (size_t)(c + 1) * s4);
        a2 += __builtin_nontemporal_load(xb + (size_t)(c + 2) * s4);
        a3 += __builtin_nontemporal_load(xb + (size_t)(c + 3) * s4);
    }
    f32x4 r = (a0 + a1) + (a2 + a3);

    unsigned int q0, q1;                 // q0 = (v1|v0<<16), q1 = (v3|v2<<16)
    asm("v_cvt_pk_bf16_f32 %0, %1, %2" : "=v"(q0) : "v"(r.y), "v"(r.x));
    asm("v_cvt_pk_bf16_f32 %0, %1, %2" : "=v"(q1) : "v"(r.w), "v"(r.z));

    int y  = p4 / 56;                 // 0..223
    int c0 = (p4 - y * 56) * 4;       // 0..220 step 4
    unsigned short* Rb_e = Re + (size_t)b * PHWr;
    unsigned short* Rb_o = Ro + (size_t)b * PHWr;

    store_quad(Rb_e, Rb_o, y + 2, c0, q0, q1);

    // row halos: y 0..3 -> rowpad 226..229 (img 224..227); y 222,223 -> 0,1
    if (y < 4)   store_quad(Rb_e, Rb_o, y + 226, c0, q0, q1);
    if (y >= 222) store_quad(Rb_e, Rb_o, y - 222, c0, q0, q1);
    // col halos: c0==0 quad also serves img cols 224..227; c0==220 serves -4..-1
    if (c0 == 0) {
        store_quad(Rb_e, Rb_o, y + 2, 224, q0, q1);
        if (y < 4)   store_quad(Rb_e, Rb_o, y + 226, 224, q0, q1);
        if (y >= 222) store_quad(Rb_e, Rb_o, y - 222, 224, q0, q1);
    }
    if (c0 == 220) {
        store_quad(Rb_e, Rb_o, y + 2, -4, q0, q1);
        if (y < 4)   store_quad(Rb_e, Rb_o, y + 226, -4, q0, q1);
        if (y >= 222) store_quad(Rb_e, Rb_o, y - 222, -4, q0, q1);
    }
}

// Conv via MFMA — B-fragments loaded directly from reversed bf16 S (4 aligned
// dword loads per fragment; no LDS, no barrier, no cvt). A-frags from W'.
// frag elem k=e lives at rev idx (Cl - x0 - lo5 - 4) + e, row = y+6-ch.
__global__ __launch_bounds__(128, 4) void conv_mfma(const unsigned short* __restrict__ Re,
                                                    const unsigned short* __restrict__ Ro,
                                                    const unsigned short* __restrict__ W,
                                                    float* __restrict__ out) {
    const int yg = blockIdx.x;           // 0..111
    const int b  = blockIdx.y;           // 0..15
    const int wv = threadIdx.x >> 6;     // 0..1
    const int l  = threadIdx.x & 63;
    const int y   = yg * 2 + wv;
    const int lo5 = l & 31;
    const int hi  = l >> 5;

    // A fragments: lane holds A[m=lo5][k = c*16 + hi*8 + j], j=0..7 (16B each)
    bf16x8 afrag[2][4];
    #pragma unroll
    for (int g = 0; g < 2; ++g)
        #pragma unroll
        for (int c = 0; c < 4; ++c)
            afrag[g][c] = *(const bf16x8*)(W + ((g * 32 + lo5) * 64 + c * 16 + hi * 8));

    const unsigned short* revb = ((lo5 & 1) ? Ro : Re) + (size_t)b * PHWr;
    const int colb = (232 + (lo5 & 1)) - lo5 - 4;     // even by construction
    int rowoff[4];
    #pragma unroll
    for (int c = 0; c < 4; ++c) rowoff[c] = (y + 6 - 2 * c - hi) * PCr;

    float* outb = out + (size_t)b * COUT_ * HWn + (size_t)y * Hn;

    #pragma unroll
    for (int xt = 0; xt < 7; ++xt) {
        const int x0 = xt * 32;

        f32x16 acc0, acc1;
        #pragma unroll
        for (int i = 0; i < 16; ++i) { acc0[i] = 0.0f; acc1[i] = 0.0f; }

        #pragma unroll
        for (int c = 0; c < 4; ++c) {
            const unsigned short* p = revb + rowoff[c] + (colb - x0);
            union { unsigned int i[4]; bf16x8 v; } bu;
            bu.i[0] = *(const unsigned int*)(p + 0);   // k 0,1
            bu.i[1] = *(const unsigned int*)(p + 2);   // k 2,3
            bu.i[2] = *(const unsigned int*)(p + 4);   // k 4,5
            bu.i[3] = *(const unsigned int*)(p + 6);   // k 6,7 (k=7 x zero wt)
            acc0 = __builtin_amdgcn_mfma_f32_32x32x16_bf16(afrag[0][c], bu.v, acc0, 0, 0, 0);
            acc1 = __builtin_amdgcn_mfma_f32_32x32x16_bf16(afrag[1][c], bu.v, acc1, 0, 0, 0);
        }

        // C/D layout: col = lo5 (pixel), row = (r&3) + 8*(r>>2) + 4*hi (oc)
        #pragma unroll
        for (int r = 0; r < 16; ++r) {
            const int row = (r & 3) + 8 * (r >> 2) + 4 * hi;
            outb[(size_t)row        * HWn + x0 + lo5] = acc0[r];
            outb[(size_t)(32 + row) * HWn + x0 + lo5] = acc1[r];
        }
    }
}

extern "C" void kernel_launch(void* const* d_in, const int* in_sizes, int n_in,
                              void* d_out, int out_size, void* d_ws, size_t ws_size,
                              hipStream_t stream) {
    const float* x = (const float*)d_in[0];   // [16,64,224,224] f32
    const float* K = (const float*)d_in[1];   // [64,64,7,7] f32
    float* out = (float*)d_out;               // [16,64,224,224] f32
    unsigned short* Re = (unsigned short*)((char*)d_ws + RE_OFF);
    unsigned short* Ro = (unsigned short*)((char*)d_ws + RO_OFF);
    unsigned short* W  = (unsigned short*)((char*)d_ws + W_OFF);

    // 784 pixel blocks + 16 wprep blocks in one launch
    chan_sum_kernel<<<800, 256, 0, stream>>>(x, Re, Ro, K, W);

    dim3 g2(112, 16);
    conv_mfma<<<g2, 128, 0, stream>>>(Re, Ro, W, out);
}

// Round 22
// 76.150 us; speedup vs baseline: 1.4896x; 1.4896x over previous
//
#include <hip/hip_runtime.h>
#include <hip/hip_bf16.h>

#define Hn 224
#define HWn (224*224)
#define B_ 16
#define CIN_ 64
#define COUT_ 64
#define PR 230            // padded rows: 2 top + 224 + 4 bottom
#define PC 240            // padded row stride in floats
#define PHW (PR*PC)
#define GUARD 1024        // floats of guard before Sp (covers row -1 reads)
#define WOFF (4*1024*1024) // byte offset of W' in d_ws

typedef __attribute__((ext_vector_type(4)))  float f32x4;
typedef __attribute__((ext_vector_type(8)))  short bf16x8;
typedef __attribute__((ext_vector_type(16))) float f32x16;

// Kernel 1 (merged): blocks 0..783 = channel-sum into padded S' with inline
// halos (nt x-loads — R12 win); blocks 784..799 = W' prep (bf16, k=ky*8+kx).
__global__ __launch_bounds__(256) void chan_sum_kernel(const float* __restrict__ x,
                                                       float* __restrict__ Sp,
                                                       const float* __restrict__ K,
                                                       unsigned short* __restrict__ W) {
    if (blockIdx.x >= 784) {            // ---- wprep tail blocks ----
        int i = (blockIdx.x - 784) * 256 + threadIdx.x;   // 0..4095
        int oc = i >> 6, kk = i & 63;
        int ky = kk >> 3, kx = kk & 7;
        float v = (ky < 7 && kx < 7) ? K[(size_t)oc * (CIN_ * 49) + ky * 7 + kx] : 0.0f;
        __hip_bfloat16 h = __float2bfloat16(v);
        W[i] = *(unsigned short*)&h;
        return;
    }

    int idx = blockIdx.x * 256 + threadIdx.x;   // < 200704 exactly
    const int s4 = HWn / 4;
    int b  = idx / s4;
    int p4 = idx - b * s4;
    const f32x4* xb = (const f32x4*)x + (size_t)b * CIN_ * s4 + p4;

    f32x4 a0 = __builtin_nontemporal_load(xb + 0 * s4);
    f32x4 a1 = __builtin_nontemporal_load(xb + 1 * s4);
    f32x4 a2 = __builtin_nontemporal_load(xb + 2 * s4);
    f32x4 a3 = __builtin_nontemporal_load(xb + 3 * s4);
    #pragma unroll 4
    for (int c = 4; c < CIN_; c += 4) {
        a0 += __builtin_nontemporal_load(xb + (size_t)(c + 0) * s4);
        a1 += __builtin_nontemporal_load(xb + (size_t)(c + 1) * s4);
        a2 += __builtin_nontemporal_load(xb + (size_t)(c + 2) * s4);
        a3 += __builtin_nontemporal_load(xb + (size_t)(c + 3) * s4);
    }
    f32x4 r = (a0 + a1) + (a2 + a3);
    float v0 = r.x, v1 = r.y, v2 = r.z, v3 = r.w;

    int y  = p4 / 56;                 // 0..223
    int x0 = (p4 - y * 56) * 4;       // 0..220 step 4
    float* Sb = Sp + (size_t)b * PHW;

    float* dst = Sb + (size_t)(y + 2) * PC + 2 + x0;
    dst[0] = v0; dst[1] = v1; dst[2] = v2; dst[3] = v3;

    if (y < 4) {
        float* d = Sb + (size_t)(y + 226) * PC + 2 + x0;
        d[0] = v0; d[1] = v1; d[2] = v2; d[3] = v3;
    }
    if (y >= 222) {
        float* d = Sb + (size_t)(y - 222) * PC + 2 + x0;
        d[0] = v0; d[1] = v1; d[2] = v2; d[3] = v3;
    }
    if (x0 == 0) {
        float* d = Sb + (size_t)(y + 2) * PC + 226;
        d[0] = v0; d[1] = v1; d[2] = v2; d[3] = v3;
        if (y < 4) {
            float* e = Sb + (size_t)(y + 226) * PC + 226;
            e[0] = v0; e[1] = v1; e[2] = v2; e[3] = v3;
        }
        if (y >= 222) {
            float* e = Sb + (size_t)(y - 222) * PC + 226;
            e[0] = v0; e[1] = v1; e[2] = v2; e[3] = v3;
        }
    }
    if (x0 == 220) {                   // x 222,223 live in lanes v2,v3
        float* d = Sb + (size_t)(y + 2) * PC;
        d[0] = v2; d[1] = v3;
        if (y < 4) {
            float* e = Sb + (size_t)(y + 226) * PC;
            e[0] = v2; e[1] = v3;
        }
        if (y >= 222) {
            float* e = Sb + (size_t)(y - 222) * PC;
            e[0] = v2; e[1] = v3;
        }
    }
}

// Conv via MFMA — LDS-staged: 256 threads = 4 waves = 4 output rows per
// block; stage 11 padded rows (yg*4-1 .. yg*4+9) once, then build
// B-fragments from LDS (ds_read + cvt_pk) instead of scattered L2 loads.
__global__ __launch_bounds__(256) void conv_mfma(const float* __restrict__ Sp,
                                                 const unsigned short* __restrict__ W,
                                                 float* __restrict__ out) {
    __shared__ float sS[11 * PC];        // 10.56 KB

    const int yg = blockIdx.x;           // 0..55
    const int b  = blockIdx.y;           // 0..15
    const int wv = threadIdx.x >> 6;     // 0..3
    const int l  = threadIdx.x & 63;
    const int y   = yg * 4 + wv;
    const int lo5 = l & 31;
    const int hi  = l >> 5;

    // stage 11 padded rows (row -1 falls in guard for yg==0: garbage x 0-weight)
    {
        const float* src = Sp + (size_t)b * PHW + (size_t)(yg * 4 - 1) * PC;
        for (int i = threadIdx.x; i < 11 * (PC / 4); i += 256) {
            int r = i / (PC / 4), c4 = i - r * (PC / 4);
            *(f32x4*)&sS[r * PC + c4 * 4] =
                *(const f32x4*)(src + (size_t)r * PC + c4 * 4);
        }
    }

    // A fragments: lane holds A[m=lo5][k = c*16 + hi*8 + j], j=0..7 (16B each)
    bf16x8 afrag[2][4];
    #pragma unroll
    for (int g = 0; g < 2; ++g)
        #pragma unroll
        for (int c = 0; c < 4; ++c)
            afrag[g][c] = *(const bf16x8*)(W + ((g * 32 + lo5) * 64 + c * 16 + hi * 8));

    __syncthreads();

    float* outb = out + (size_t)b * COUT_ * HWn + (size_t)y * Hn;

    for (int xt = 0; xt < 7; ++xt) {
        const int x0 = xt * 32;

        f32x16 acc0, acc1;
        #pragma unroll
        for (int i = 0; i < 16; ++i) { acc0[i] = 0.0f; acc1[i] = 0.0f; }

        #pragma unroll
        for (int c = 0; c < 4; ++c) {
            // B fragment from LDS: ch = 2c+hi, LDS row = wv + 7 - ch
            // (staging origin yg*4-1; y - yg*4 = wv).
            const float* rp = &sS[(wv + 7 - (2 * c + hi)) * PC + x0 + 6 + lo5];
            union { int i[4]; bf16x8 v; } bu;
            #pragma unroll
            for (int j = 0; j < 4; ++j) {
                float flo = rp[-(2 * j)];        // kx = 2j
                float fhi = rp[-(2 * j) - 1];    // kx = 2j+1
                asm("v_cvt_pk_bf16_f32 %0, %1, %2" : "=v"(bu.i[j]) : "v"(flo), "v"(fhi));
            }
            acc0 = __builtin_amdgcn_mfma_f32_32x32x16_bf16(afrag[0][c], bu.v, acc0, 0, 0, 0);
            acc1 = __builtin_amdgcn_mfma_f32_32x32x16_bf16(afrag[1][c], bu.v, acc1, 0, 0, 0);
        }

        // C/D layout: col = lo5 (pixel), row = (r&3) + 8*(r>>2) + 4*hi (oc)
        #pragma unroll
        for (int r = 0; r < 16; ++r) {
            const int row = (r & 3) + 8 * (r >> 2) + 4 * hi;
            outb[(size_t)row        * HWn + x0 + lo5] = acc0[r];
            outb[(size_t)(32 + row) * HWn + x0 + lo5] = acc1[r];
        }
    }
}

extern "C" void kernel_launch(void* const* d_in, const int* in_sizes, int n_in,
                              void* d_out, int out_size, void* d_ws, size_t ws_size,
                              hipStream_t stream) {
    const float* x = (const float*)d_in[0];   // [16,64,224,224] f32
    const float* K = (const float*)d_in[1];   // [64,64,7,7] f32
    float* out = (float*)d_out;               // [16,64,224,224] f32
    float* Sp = (float*)d_ws + GUARD;         // padded S' with guard
    unsigned short* W = (unsigned short*)((char*)d_ws + WOFF);

    // 784 pixel blocks + 16 wprep blocks in one launch
    chan_sum_kernel<<<800, 256, 0, stream>>>(x, Sp, K, W);

    dim3 g2(56, 16);
    conv_mfma<<<g2, 256, 0, stream>>>(Sp, W, out);
}